// Round 4
// baseline (288.466 us; speedup 1.0000x reference)
//
#include <hip/hip_runtime.h>
#include <stdint.h>
#include <math.h>

// Problem shape (fixed by reference): xs [B,T,N,D] fp32, A [1,N,N] int32
#define BB 4
#define TT 32
#define NN 128
#define DD 32
#define NPB 16                       // nodes per block (16 nodes x 32 d = 512 threads)
#define TPB (NPB * DD)               // 512 threads
#define NBLK (BB * TT * (NN / NPB))  // 1024 blocks = exactly 4 per CU
#define CAP 16                       // band capacity incl temporal; overflow -> exact fallback
#define NK (CAP + 2)                 // 16 spatial slots + 2 temporal slots

// Arithmetic 8-bin partition of the value axis. ANY monotone non-decreasing
// bin function gives exact rank selection (equal values -> equal bins, so
// bins partition the multiset in value order). Median of ~66 N(0,1) lands in
// a bin with count <= CAP except ~1e-6/lane -> fallback is exact anyway.
__device__ __forceinline__ int bin8(float x) {
    int i = (int)fmaf(x, 5.0f, 4.0f);   // trunc; monotone non-decreasing
    i = i < 0 ? 0 : i;
    return i > 7 ? 7 : i;
}

// Adjacency row of each node as a 128-bit mask (A row nonzero | self loop).
// build_adj already computes exactly this via ballot -- store it raw.
__global__ __launch_bounds__(64) void build_adj_kernel(const int* __restrict__ A,
                                                       unsigned long long* __restrict__ mask) {
    const int n = blockIdx.x;
    const int lane = threadIdx.x;  // 0..63
    const int* arow = A + n * NN;
    const bool b0 = (arow[lane] != 0) || (lane == n);
    const bool b1 = (arow[lane + 64] != 0) || (lane + 64 == n);
    const unsigned long long m0 = __ballot(b0);
    const unsigned long long m1 = __ballot(b1);
    if (lane == 0) { mask[n * 2] = m0; mask[n * 2 + 1] = m1; }
}

// R4 bitset redesign. R0-R3 all ~75us: latency-bound on 66-iteration
// dependent LDS chains with ~2 waves/SIMD effective residency; instruction
// and LDS-size tweaks were flat. This version removes the chains:
//  - histogram = popcount(adj128 & binplane128): 8 ds_read_b128 total
//  - band extraction = ffs-walk of a 128-bit register mask; sval reads are
//    bank-conflict-free by construction (bank == d)
//  - ranking fully in registers (ki[18], scalar counts)
// Per-thread DS ops ~300 -> ~35. LDS 31.7KB -> 20.5KB.
__global__ __launch_bounds__(TPB) void median_kernel(const float* __restrict__ xs,
                                                     const unsigned long long* __restrict__ mask,
                                                     float* __restrict__ out) {
    __shared__ __align__(16) float sval[NN * DD];          // 16 KB: current frame [n][d]
    __shared__ __align__(16) unsigned int sbit[8 * DD * 4]; // 4 KB: bitplanes [bin][d][n/32]

    const int tid = threadIdx.x;
    // Bijective XCD swizzle (NBLK % 8 == 0): contiguous logical chunk per XCD.
    const int bid = blockIdx.x;
    const int g = ((bid & 7) << 7) | (bid >> 3);
    const int ng = g & (NN / NPB - 1);       // % 8
    const int t  = (g >> 3) & (TT - 1);      // /8 % 32
    const int b  = g >> 8;                   // /256
    const int n0 = ng * NPB;

    const int d = tid & (DD - 1);
    const int nl = tid >> 5;  // local node 0..15
    const int n = n0 + nl;
    const int pv = (t > 0) ? 1 : 0;        // wave-uniform
    const int nv = (t < TT - 1) ? 1 : 0;   // wave-uniform
    const int ne = pv + nv;

    // temporal candidates (coalesced; issued before the barriers)
    float exv0 = 0.0f, exv1 = 0.0f;
    if (pv) exv0 = xs[(((size_t)(b * TT + t - 1) * NN) + n) * DD + d];
    if (nv) {
        float v = xs[(((size_t)(b * TT + t + 1) * NN) + n) * DD + d];
        if (pv) exv1 = v; else exv0 = v;
    }

    // zero bitplanes: 1024 words / 512 threads = 1 uint2 each
    ((uint2*)sbit)[tid] = make_uint2(0u, 0u);

    // stage current frame (float4 coalesced); bins computed from registers
    const float4* src4 = (const float4*)(xs + ((size_t)(b * TT + t) * NN) * DD);
    const float4 f0 = src4[tid];
    const float4 f1 = src4[tid + 512];
    ((float4*)sval)[tid] = f0;
    ((float4*)sval)[tid + 512] = f1;

    __syncthreads();  // sbit zeroing complete before atomics

    // scatter bin bits. element e = tid*4+q (+2048 for f1): en=e>>5, ed=e&31.
    // word = bin*128 + ed*4 + (en>>5), bit en&31. 4-aligned => en uniform per float4.
    {
        const int e0 = tid * 4;
        const int en = e0 >> 5;
        const int ed = e0 & 31;
        const unsigned int bm = 1u << (en & 31);
        const int wo = en >> 5;
        atomicOr(&sbit[bin8(f0.x) * 128 + (ed + 0) * 4 + wo], bm);
        atomicOr(&sbit[bin8(f0.y) * 128 + (ed + 1) * 4 + wo], bm);
        atomicOr(&sbit[bin8(f0.z) * 128 + (ed + 2) * 4 + wo], bm);
        atomicOr(&sbit[bin8(f0.w) * 128 + (ed + 3) * 4 + wo], bm);
        const int en1 = en + 64;   // +2048 elements = +64 nodes
        const unsigned int bm1 = 1u << (en1 & 31);
        const int wo1 = en1 >> 5;
        atomicOr(&sbit[bin8(f1.x) * 128 + (ed + 0) * 4 + wo1], bm1);
        atomicOr(&sbit[bin8(f1.y) * 128 + (ed + 1) * 4 + wo1], bm1);
        atomicOr(&sbit[bin8(f1.z) * 128 + (ed + 2) * 4 + wo1], bm1);
        atomicOr(&sbit[bin8(f1.w) * 128 + (ed + 3) * 4 + wo1], bm1);
    }
    __syncthreads();  // bitplanes + sval visible

    // adjacency mask for this node (16B, broadcast across the 32 lanes of a node)
    const uint4 am4 = *((const uint4*)(mask + (size_t)n * 2));
    const unsigned int a0 = am4.x, a1 = am4.y, a2 = am4.z, a3 = am4.w;
    const unsigned long long am0 = (((unsigned long long)a1) << 32) | a0;
    const unsigned long long am1 = (((unsigned long long)a3) << 32) | a2;
    const int dg = __popcll(am0) + __popcll(am1);
    const int k = dg + ne;
    const uint32_t r = (uint32_t)((k - 1) >> 1);  // lower-median rank (0-based)
    const int be0 = bin8(exv0);
    const int be1 = bin8(exv1);
    const float INFV = __uint_as_float(0x7F800000u);

    // ---- histogram: 8 x (b128 read, AND, popcount-accumulate) ----
    int hist[8];
    const uint4* sbit4 = (const uint4*)sbit;
    #pragma unroll
    for (int bb = 0; bb < 8; ++bb) {
        uint4 w = sbit4[bb * 32 + d];
        hist[bb] = __popc(w.x & a0) + __popc(w.y & a1) + __popc(w.z & a2) + __popc(w.w & a3);
    }

    // ---- prefix over bins (temporal folded in statically); select rank bin ----
    uint32_t cum = 0, lowcnt = 0, mexp = 0;
    int selbin = -1;
    #pragma unroll
    for (int bb = 0; bb < 8; ++bb) {
        uint32_t bc = (uint32_t)hist[bb] + ((ne >= 1 && be0 == bb) ? 1u : 0u)
                                         + ((ne == 2 && be1 == bb) ? 1u : 0u);
        uint32_t nc = cum + bc;
        if (selbin < 0 && r < nc) { selbin = bb; lowcnt = cum; mexp = bc; }
        cum = nc;
    }
    const bool fb = (mexp > CAP);   // band too big -> exact fallback (~never)
    const uint32_t rp = r - lowcnt; // rank within band

    // ---- band mask: re-read selected bitplane (selbin is an address, not a
    // register index), AND with adjacency -> 128-bit register mask ----
    const int sb = fb ? 0 : selbin;
    uint4 ws = sbit4[sb * 32 + d];
    unsigned long long bm0 = (((unsigned long long)(ws.y & a1)) << 32) | (ws.x & a0);
    unsigned long long bm1 = (((unsigned long long)(ws.w & a3)) << 32) | (ws.z & a2);
    const int mc_sp = fb ? 0 : (__popcll(bm0) + __popcll(bm1));

    // ---- extract band values: static ffs-walk; sval bank == d (conflict-free) ----
    float ki[NK];
    #pragma unroll
    for (int u = 0; u < CAP; ++u) {
        const bool lo = (bm0 != 0ull);
        const unsigned long long mm_ = lo ? bm0 : bm1;
        const int ff = __ffsll((unsigned long long)mm_) - 1;  // -1 when empty
        const int id = ((lo ? ff : 64 + ff) & 127);
        const float v = sval[id * DD + d];
        ki[u] = (u < mc_sp) ? v : INFV;
        const unsigned long long cl = mm_ & (mm_ - 1ull);
        bm0 = lo ? cl : bm0;
        bm1 = lo ? bm1 : cl;
    }
    const bool t0 = (ne >= 1) && (be0 == selbin) && !fb;
    const bool t1 = (ne == 2) && (be1 == selbin) && !fb;
    ki[CAP]     = t0 ? exv0 : INFV;
    ki[CAP + 1] = t1 ? exv1 : INFV;

    // ---- rank within band: all-pairs strict-less, scalar count per slot ----
    // (INF slots contribute 0 to finite counts; invalid slots never selected)
    float result = 0.0f;
    bool found = fb;
    #pragma unroll
    for (int u = 0; u < NK; ++u) {
        uint32_t cnu = 0;
        #pragma unroll
        for (int v = 0; v < NK; ++v) cnu += (ki[v] < ki[u]) ? 1u : 0u;
        const bool valid = (u < CAP) ? (u < mc_sp) : ((u == CAP) ? t0 : t1);
        if (!found && valid && cnu == rp) { result = ki[u]; found = true; }
    }

    // ---- duplicate-median pass (exact multiset lower-median; ~never runs) ----
    if (__ballot(!found)) {
        #pragma unroll
        for (int u = 0; u < NK; ++u) {
            uint32_t cnu = 0, equ = 0;
            #pragma unroll
            for (int v = 0; v < NK; ++v) {
                cnu += (ki[v] < ki[u]) ? 1u : 0u;
                equ += (ki[v] == ki[u]) ? 1u : 0u;  // includes self
            }
            const bool valid = (u < CAP) ? (u < mc_sp) : ((u == CAP) ? t0 : t1);
            if (!found && valid && cnu <= rp && rp < cnu + equ) {
                result = ki[u]; found = true;
            }
        }
    }

    // ---- full fallback (band > CAP; ~1e-6 of lanes): exact over all k ----
    if (__ballot(fb)) {
        bool done = !fb;
        for (int i0 = 0; __ballot(!done && i0 < NN + 2); i0 += 8) {
            float k8[8]; uint32_t c8[8];
            #pragma unroll
            for (int u = 0; u < 8; ++u) {
                const int i = i0 + u;
                const unsigned long long src = (i < 64) ? am0 : am1;
                const bool memsp = ((src >> (i & 63)) & 1ull) != 0ull;
                const bool mem = (i < 128) ? memsp
                               : ((i == 128) ? (ne >= 1) : ((i == 129) ? (ne == 2) : false));
                const float v = (i < 128) ? sval[(i & 127) * DD + d]
                                          : ((i == 128) ? exv0 : exv1);
                k8[u] = mem ? v : INFV;
                c8[u] = 0;
            }
            for (int j = 0; j < NN; ++j) {
                const unsigned long long srcj = (j < 64) ? am0 : am1;
                const bool mj = ((srcj >> (j & 63)) & 1ull) != 0ull;
                const float x = mj ? sval[j * DD + d] : INFV;  // INF < k8 never true
                #pragma unroll
                for (int u = 0; u < 8; ++u) c8[u] += (x < k8[u]) ? 1u : 0u;
            }
            if (ne >= 1) {
                #pragma unroll
                for (int u = 0; u < 8; ++u) c8[u] += (exv0 < k8[u]) ? 1u : 0u;
            }
            if (ne == 2) {
                #pragma unroll
                for (int u = 0; u < 8; ++u) c8[u] += (exv1 < k8[u]) ? 1u : 0u;
            }
            #pragma unroll
            for (int u = 0; u < 8; ++u) {
                if (!done && k8[u] < INFV && c8[u] == r) { result = k8[u]; done = true; }
            }
        }
        if (__ballot(!done)) {  // duplicates across rank: exact multiset selection
            for (int i0 = 0; __ballot(!done && i0 < NN + 2); i0 += 4) {
                float k4[4]; uint32_t lt4[4], le4[4];
                #pragma unroll
                for (int u = 0; u < 4; ++u) {
                    const int i = i0 + u;
                    const unsigned long long src = (i < 64) ? am0 : am1;
                    const bool memsp = ((src >> (i & 63)) & 1ull) != 0ull;
                    const bool mem = (i < 128) ? memsp
                                   : ((i == 128) ? (ne >= 1) : ((i == 129) ? (ne == 2) : false));
                    const float v = (i < 128) ? sval[(i & 127) * DD + d]
                                              : ((i == 128) ? exv0 : exv1);
                    k4[u] = mem ? v : INFV;
                    lt4[u] = 0; le4[u] = 0;
                }
                for (int j = 0; j < NN; ++j) {
                    const unsigned long long srcj = (j < 64) ? am0 : am1;
                    const bool mj = ((srcj >> (j & 63)) & 1ull) != 0ull;
                    const float x = mj ? sval[j * DD + d] : INFV;
                    #pragma unroll
                    for (int u = 0; u < 4; ++u) {
                        lt4[u] += (x < k4[u]) ? 1u : 0u;
                        le4[u] += (x <= k4[u]) ? 1u : 0u;  // INF<=finite false
                    }
                }
                if (ne >= 1) {
                    #pragma unroll
                    for (int u = 0; u < 4; ++u) {
                        lt4[u] += (exv0 < k4[u]) ? 1u : 0u;
                        le4[u] += (exv0 <= k4[u]) ? 1u : 0u;
                    }
                }
                if (ne == 2) {
                    #pragma unroll
                    for (int u = 0; u < 4; ++u) {
                        lt4[u] += (exv1 < k4[u]) ? 1u : 0u;
                        le4[u] += (exv1 <= k4[u]) ? 1u : 0u;
                    }
                }
                #pragma unroll
                for (int u = 0; u < 4; ++u) {
                    if (!done && k4[u] < INFV && lt4[u] <= r && r < le4[u]) {
                        result = k4[u]; done = true;
                    }
                }
            }
        }
    }

    out[(((size_t)(b * TT + t) * NN) + n) * DD + d] = result;
}

extern "C" void kernel_launch(void* const* d_in, const int* in_sizes, int n_in,
                              void* d_out, int out_size, void* d_ws, size_t ws_size,
                              hipStream_t stream) {
    const float* xs = (const float*)d_in[0];
    const int* A = (const int*)d_in[1];
    float* out = (float*)d_out;

    // workspace layout: mask[128][2] u64 (2 KB)
    unsigned long long* mask = (unsigned long long*)d_ws;

    build_adj_kernel<<<NN, 64, 0, stream>>>(A, mask);
    median_kernel<<<NBLK, TPB, 0, stream>>>(xs, mask, out);
}